// Round 1
// baseline (32.879 us; speedup 1.0000x reference)
//
#include <hip/hip_runtime.h>

// RankPool1d: window=16, stride=1, pad=8 (zeros), rank=8th smallest (0-based 7),
// stable argsort tie-breaking. Outputs: values f32 [OUT_LEN], sel (as f32) [OUT_LEN].

constexpr int L_IN    = 4194304;
constexpr int OUT_LEN = L_IN + 1;     // (L + 2*8 - 16)/1 + 1
constexpr int MOUT    = 16;           // outputs per thread (sliding reuse)

__global__ __launch_bounds__(256) void rankpool_kernel(const float* __restrict__ x,
                                                       float* __restrict__ dout) {
    const int tid = blockIdx.x * blockDim.x + threadIdx.x;
    const int o0  = tid * MOUT;                  // first output index of this thread
    if (o0 >= OUT_LEN) return;
    const int base = o0 - 8;                     // global index of w[0] (may be <0)

    // ---- load 32 inputs (windows [m, m+15] for m=0..15 need base..base+30) ----
    float w[32];
    if (base >= 0 && base + 32 <= L_IN) {
        // base = 16*tid - 8 -> byte offset 64*tid - 32, 16B-aligned
        const float4* p = reinterpret_cast<const float4*>(x + base);
        #pragma unroll
        for (int q = 0; q < 8; ++q) {
            float4 v = p[q];
            w[4*q+0] = v.x; w[4*q+1] = v.y; w[4*q+2] = v.z; w[4*q+3] = v.w;
        }
    } else {
        #pragma unroll
        for (int t = 0; t < 32; ++t) {
            int g = base + t;
            w[t] = (g >= 0 && g < L_IN) ? x[g] : 0.0f;   // PAD_VALUE = 0
        }
    }

    // ---- initial ranks for window 0 (elements 0..15), stable tie-break ----
    // rank[j] = #{k in window : (w[k],k) < (w[j],j)}  (lexicographic)
    int rk[31];
    #pragma unroll
    for (int j = 0; j < 16; ++j) rk[j] = 0;
    #pragma unroll
    for (int j = 0; j < 16; ++j) {
        #pragma unroll
        for (int k = j + 1; k < 16; ++k) {
            // j < k: k before j  iff  w[k] <  w[j]
            //        j before k  iff  w[j] <= w[k]  == !(w[k] < w[j])
            int c = (w[k] < w[j]);
            rk[j] += c;
            rk[k] += 1 - c;
        }
    }

    float va[MOUT];
    int   sa[MOUT];
    #pragma unroll
    for (int m = 0; m < MOUT; ++m) {
        // ---- select element with rank == 7 in window [m, m+15] ----
        int   sel = 0;
        float val = w[m];
        #pragma unroll
        for (int j = m; j < m + 16; ++j) {
            bool c = (rk[j] == 7);
            sel = c ? (j - m) : sel;
            val = c ? w[j]    : val;
        }
        va[m] = val;
        sa[m] = sel;

        // ---- slide: remove w[m] (oldest index), add w[m+16] (newest index) ----
        if (m < MOUT - 1) {
            int s = 0;
            #pragma unroll
            for (int j = m + 1; j < m + 16; ++j) {
                // removal: departed (oldest) was before j iff dep <= w[j],
                //          i.e. rank -= 1 - (w[j] < dep)
                int c1 = (w[j] < w[m]);
                // insertion: newest is before j iff new < w[j] (strict)
                int c2 = (w[m + 16] < w[j]);
                rk[j] += c1 - 1 + c2;
                s     += c2;
            }
            // rank(new) = #{existing j : w[j] <= new} = 15 - #{new < w[j]}
            rk[m + 16] = 15 - s;
        }
    }

    // ---- stores ----
    if (o0 + MOUT <= OUT_LEN) {
        // values: o0 is a multiple of 16 -> 64B-aligned float4 stores
        float4* pv = reinterpret_cast<float4*>(dout + o0);
        #pragma unroll
        for (int q = 0; q < 4; ++q)
            pv[q] = make_float4(va[4*q], va[4*q+1], va[4*q+2], va[4*q+3]);
        // sel region starts at odd offset OUT_LEN + o0 -> scalar stores
        float* ps = dout + OUT_LEN + o0;
        #pragma unroll
        for (int m = 0; m < MOUT; ++m)
            ps[m] = (float)sa[m];
    } else {
        #pragma unroll
        for (int m = 0; m < MOUT; ++m) {
            if (o0 + m < OUT_LEN) {
                dout[o0 + m]           = va[m];
                dout[OUT_LEN + o0 + m] = (float)sa[m];
            }
        }
    }
}

extern "C" void kernel_launch(void* const* d_in, const int* in_sizes, int n_in,
                              void* d_out, int out_size, void* d_ws, size_t ws_size,
                              hipStream_t stream) {
    const float* x = (const float*)d_in[0];
    float* out = (float*)d_out;
    const int threads = (OUT_LEN + MOUT - 1) / MOUT;   // 262145
    const int blocks  = (threads + 255) / 256;         // 1025
    rankpool_kernel<<<blocks, 256, 0, stream>>>(x, out);
}

// Round 2
// 25.653 us; speedup vs baseline: 1.2817x; 1.2817x over previous
//
#include <hip/hip_runtime.h>

// RankPool1d: window=16, stride=1, pad=8 (zeros), rank=8 (0-based 7),
// stable argsort tie-break. Outputs: values f32 [OUT_LEN], sel (as f32) [OUT_LEN].
//
// Each thread: 16 consecutive outputs via incremental rank maintenance.
// Biased ranks R[j] = rank_in_window + window_idx  =>  slide update is two
// bool-adds, target is compile-time (7+m). Outputs transposed through LDS so
// ALL global stores are float4 (sel half via +1-shifted LDS buffer to fix the
// odd OUT_LEN alignment).

constexpr int L_IN    = 4194304;
constexpr int OUT_LEN = L_IN + 1;      // 4194305
constexpr int MOUT    = 16;            // outputs per thread
constexpr int TPB     = 256;
constexpr int OPB     = TPB * MOUT;    // 4096 outputs per block

__global__ __launch_bounds__(TPB) void rankpool_kernel(const float* __restrict__ x,
                                                       float* __restrict__ dout) {
    __shared__ __align__(16) float lv[OPB];      // values
    __shared__ __align__(16) float ls[OPB + 2];  // sel, shifted +1 word

    const int t    = threadIdx.x;
    const int blk  = blockIdx.x;
    const int o0   = (blk * TPB + t) * MOUT;
    const int base = o0 - 8;
    const bool lastBlock = (blk == (int)gridDim.x - 1);

    // ---- load 32 inputs (covers windows m=0..15: base..base+30) ----
    float w[32];
    if (base >= 0 && base + 32 <= L_IN) {
        const float4* p = reinterpret_cast<const float4*>(x + base); // 16B aligned
        #pragma unroll
        for (int q = 0; q < 8; ++q) {
            float4 v = p[q];
            w[4*q+0] = v.x; w[4*q+1] = v.y; w[4*q+2] = v.z; w[4*q+3] = v.w;
        }
    } else {
        #pragma unroll
        for (int i = 0; i < 32; ++i) {
            int g = base + i;
            w[i] = (g >= 0 && g < L_IN) ? x[g] : 0.0f;   // PAD_VALUE = 0
        }
    }

    // ---- biased ranks for window 0: R[j] = rank (stable) ----
    // init R[k]=k absorbs the "+1-c" side of each pair into a single -=c.
    int R[31];
    #pragma unroll
    for (int j = 0; j < 16; ++j) R[j] = j;
    #pragma unroll
    for (int j = 0; j < 16; ++j) {
        #pragma unroll
        for (int k = j + 1; k < 16; ++k) {
            int c = (w[k] < w[j]);
            R[j] += c;
            R[k] -= c;
        }
    }

    // ---- per-window select (rank==7 <=> R[j]==7+m) + slide ----
    #pragma unroll
    for (int m = 0; m < MOUT; ++m) {
        int   sel = 0;
        float val = w[m];
        #pragma unroll
        for (int j = m; j < m + 16; ++j) {
            bool c = (R[j] == 7 + m);
            sel = c ? (j - m) : sel;
            val = c ? w[j]    : val;
        }
        if (!lastBlock) {
            lv[t * MOUT + m]     = val;
            ls[t * MOUT + m + 1] = (float)sel;
        } else if (o0 + m < OUT_LEN) {
            dout[o0 + m]           = val;
            dout[OUT_LEN + o0 + m] = (float)sel;
        }

        if (m < MOUT - 1) {
            const float wm = w[m];        // departing (oldest index)
            const float wn = w[m + 16];   // entering (newest index)
            int s = 0;
            #pragma unroll
            for (int j = m + 1; j < m + 16; ++j) {
                R[j] += (int)(w[j] < wm);   // departed NOT before j
                int c2 = (wn < w[j]);       // new strictly before j
                R[j] += c2;
                s    += c2;
            }
            R[m + 16] = 16 + m - s;         // (15 - s) + (m+1) bias
        }
    }

    // ---- cooperative vectorized stores ----
    if (!lastBlock) {
        __syncthreads();
        const int blockStart = blk * OPB;

        // values: fully aligned float4
        #pragma unroll
        for (int k = 0; k < 4; ++k) {
            int i = t + k * TPB;                       // 0..1023
            float4 v = *reinterpret_cast<const float4*>(&lv[4 * i]);
            *reinterpret_cast<float4*>(dout + blockStart + 4 * i) = v;
        }

        // sel: global base g0 = OUT_LEN + blockStart  (== 1 mod 4)
        float* s0 = dout + OUT_LEN + blockStart;
        if (t < 3)  s0[t] = ls[t + 1];                 // j = 0,1,2
        if (t == 3) s0[OPB - 1] = ls[OPB];             // j = 4095
        #pragma unroll
        for (int k = 0; k < 4; ++k) {
            int p = t + k * TPB;                       // float4 index
            if (p < (OPB - 4) / 4 + 1 - 1) {           // p < 1023
                float4 v = *reinterpret_cast<const float4*>(&ls[4 + 4 * p]);
                *reinterpret_cast<float4*>(s0 + 3 + 4 * p) = v;   // 16B aligned
            }
        }
    }
}

extern "C" void kernel_launch(void* const* d_in, const int* in_sizes, int n_in,
                              void* d_out, int out_size, void* d_ws, size_t ws_size,
                              hipStream_t stream) {
    const float* x = (const float*)d_in[0];
    float* out = (float*)d_out;
    const int threads = (OUT_LEN + MOUT - 1) / MOUT;   // 262145
    const int blocks  = (threads + TPB - 1) / TPB;     // 1025
    rankpool_kernel<<<blocks, TPB, 0, stream>>>(x, out);
}

// Round 3
// 23.381 us; speedup vs baseline: 1.4062x; 1.0972x over previous
//
#include <hip/hip_runtime.h>

// RankPool1d: window=16, stride=1, pad=8 (zeros), rank=8 (0-based 7),
// stable argsort tie-break. Outputs: values f32 [OUT_LEN], sel (as f32) [OUT_LEN].
//
// Per thread: 16 consecutive outputs via sliding rank maintenance (biased
// ranks R[j] = rank + window_idx -> slide is two carry-adds, threshold 7+m).
// Outputs transposed through COLUMN-MAJOR LDS (val[m][t]): ds_write lane
// stride 4B = conflict-free, compile-time offset immediates. Global stores
// float4-aligned for both output halves.

constexpr int L_IN    = 4194304;
constexpr int OUT_LEN = L_IN + 1;      // 4194305
constexpr int MOUT    = 16;            // outputs per thread
constexpr int TPB     = 256;
constexpr int OPB     = TPB * MOUT;    // 4096 outputs per block

__global__ __launch_bounds__(TPB) void rankpool_kernel(const float* __restrict__ x,
                                                       float* __restrict__ dout) {
    __shared__ float lv[MOUT * TPB];   // values, [m][t]
    __shared__ float ls[MOUT * TPB];   // sel,    [m][t]

    const int t   = threadIdx.x;
    const int blk = blockIdx.x;

    // ---- last block: exactly one valid output (o = OUT_LEN-1) ----
    if (blk == 1024) {
        if (t == 0) {
            float w[16];
            #pragma unroll
            for (int i = 0; i < 16; ++i) {
                int g = L_IN - 8 + i;
                w[i] = (g < L_IN) ? x[g] : 0.0f;
            }
            int R[16];
            #pragma unroll
            for (int j = 0; j < 16; ++j) R[j] = j;
            #pragma unroll
            for (int j = 0; j < 16; ++j)
                #pragma unroll
                for (int k = j + 1; k < 16; ++k) {
                    int c = (w[k] < w[j]);
                    R[j] += c; R[k] -= c;
                }
            int sel = 0; float val = w[0];
            #pragma unroll
            for (int j = 0; j < 16; ++j) {
                bool c = (R[j] == 7);
                sel = c ? j : sel; val = c ? w[j] : val;
            }
            dout[OUT_LEN - 1]     = val;
            dout[2 * OUT_LEN - 1] = (float)sel;
        }
        return;
    }

    const int o0   = (blk * TPB + t) * MOUT;
    const int base = o0 - 8;

    // ---- load 32 inputs (windows m=0..15 need base..base+30) ----
    float w[32];
    if (base >= 0 && base + 32 <= L_IN) {
        const float4* p = reinterpret_cast<const float4*>(x + base); // 16B aligned
        #pragma unroll
        for (int q = 0; q < 8; ++q) {
            float4 v = p[q];
            w[4*q+0] = v.x; w[4*q+1] = v.y; w[4*q+2] = v.z; w[4*q+3] = v.w;
        }
    } else {
        #pragma unroll
        for (int i = 0; i < 32; ++i) {
            int g = base + i;
            w[i] = (g >= 0 && g < L_IN) ? x[g] : 0.0f;   // PAD_VALUE = 0
        }
    }

    // ---- biased ranks for window 0 ----
    int R[31];
    #pragma unroll
    for (int j = 0; j < 16; ++j) R[j] = j;
    #pragma unroll
    for (int j = 0; j < 16; ++j) {
        #pragma unroll
        for (int k = j + 1; k < 16; ++k) {
            int c = (w[k] < w[j]);
            R[j] += c;
            R[k] -= c;
        }
    }

    // ---- per-window select + slide; conflict-free column-major LDS writes ----
    #pragma unroll
    for (int m = 0; m < MOUT; ++m) {
        int   sel = 0;
        float val = w[m];
        #pragma unroll
        for (int j = m; j < m + 16; ++j) {
            bool c = (R[j] == 7 + m);
            sel = c ? (j - m) : sel;
            val = c ? w[j]    : val;
        }
        lv[m * TPB + t] = val;          // bank = t%32 -> 2-way, free
        ls[m * TPB + t] = (float)sel;

        if (m < MOUT - 1) {
            const float wm = w[m];
            const float wn = w[m + 16];
            int s = 0;
            #pragma unroll
            for (int j = m + 1; j < m + 16; ++j) {
                R[j] += (int)(w[j] < wm);
                int c2 = (wn < w[j]);
                R[j] += c2;
                s    += c2;
            }
            R[m + 16] = 16 + m - s;
        }
    }

    __syncthreads();

    // ---- cooperative float4 global stores, scalar LDS gathers ----
    const int blockStart = blk * OPB;

    // values: aligned
    #pragma unroll
    for (int k = 0; k < 4; ++k) {
        int p = 4 * (t + 256 * k);      // multiple of 4
        float4 v;
        v.x = lv[((p + 0) & 15) * TPB + ((p + 0) >> 4)];
        v.y = lv[((p + 1) & 15) * TPB + ((p + 1) >> 4)];
        v.z = lv[((p + 2) & 15) * TPB + ((p + 2) >> 4)];
        v.w = lv[((p + 3) & 15) * TPB + ((p + 3) >> 4)];
        *reinterpret_cast<float4*>(dout + blockStart + p) = v;
    }

    // sel: global base g0 = OUT_LEN + blockStart (== 1 mod 4); shift +3 aligns
    float* s0 = dout + OUT_LEN + blockStart;
    if (t < 3)  s0[t] = ls[t * TPB];                    // p = 0,1,2 (tp = 0)
    if (t == 3) s0[OPB - 1] = ls[15 * TPB + 255];       // p = 4095
    #pragma unroll
    for (int k = 0; k < 4; ++k) {
        int q = t + 256 * k;            // chunk index
        if (q < 1023) {
            int p = 3 + 4 * q;          // elements p..p+3
            float4 v;
            v.x = ls[((p + 0) & 15) * TPB + ((p + 0) >> 4)];
            v.y = ls[((p + 1) & 15) * TPB + ((p + 1) >> 4)];
            v.z = ls[((p + 2) & 15) * TPB + ((p + 2) >> 4)];
            v.w = ls[((p + 3) & 15) * TPB + ((p + 3) >> 4)];
            *reinterpret_cast<float4*>(s0 + p) = v;     // 16B aligned
        }
    }
}

extern "C" void kernel_launch(void* const* d_in, const int* in_sizes, int n_in,
                              void* d_out, int out_size, void* d_ws, size_t ws_size,
                              hipStream_t stream) {
    const float* x = (const float*)d_in[0];
    float* out = (float*)d_out;
    rankpool_kernel<<<1025, TPB, 0, stream>>>(x, out);
}